// Round 1
// baseline (2058.604 us; speedup 1.0000x reference)
//
#include <hip/hip_runtime.h>
#include <math.h>

#define DDIM 512
#define TM 64
#define TN 128
#define KB 32
#define NSPLITS 64
#define LDA_PITCH 68   // KB x 68  (pad: multiple of 4 for aligned float4, 2-way banks)
#define LDB_PITCH 132  // KB x 132
#define SIMS_PITCH 133 // TM x 133 (odd*... gives 2-way banks on column scans)
#define SMEM_FLOATS 8512
#define NEG_INF (-3.0e38f)

__global__ __launch_bounds__(256) void row_rnorm_k(const float* __restrict__ x,
                                                   float* __restrict__ rn, int rows) {
    int wave = threadIdx.x >> 6;
    int lane = threadIdx.x & 63;
    int row = blockIdx.x * 4 + wave;
    if (row >= rows) return;
    const float* p = x + (size_t)row * DDIM + lane * 4;
    float4 a = *(const float4*)p;
    float4 b = *(const float4*)(p + 256);
    float s = a.x*a.x + a.y*a.y + a.z*a.z + a.w*a.w
            + b.x*b.x + b.y*b.y + b.z*b.z + b.w*b.w;
    #pragma unroll
    for (int off = 32; off > 0; off >>= 1) s += __shfl_xor(s, off, 64);
    if (lane == 0) rn[row] = 1.0f / fmaxf(sqrtf(s), 1e-12f);
}

__global__ __launch_bounds__(256) void gemm_topk_k(
    const float* __restrict__ z, const float* __restrict__ bank,
    const float* __restrict__ rz, const float* __restrict__ rb,
    float* __restrict__ cand_v, int* __restrict__ cand_i,
    int B, int N, int nChunks) {
    __shared__ float smem[SMEM_FLOATS];
    float* LA  = smem;                    // [KB][LDA_PITCH]
    float* LB  = smem + KB * LDA_PITCH;   // [KB][LDB_PITCH]
    float* SIM = smem;                    // [TM][SIMS_PITCH] (aliases staging; barriers guard)

    const int t  = threadIdx.x;
    const int tx = t & 15;   // col group: cols tx*4..+3 and 64+tx*4..+3
    const int ty = t >> 4;   // row group: rows ty*4..+3
    const int rowBase = blockIdx.x * TM;
    const int split   = blockIdx.y;

    const int ar = t >> 2, akg = t & 3;   // A staging: row ar, k-offsets akg*4 (+16)
    const int br = t >> 1, bkg = t & 1;   // B staging: row br, k-offsets bkg*16 + q*4

    float rzv[4];
    #pragma unroll
    for (int u = 0; u < 4; ++u) rzv[u] = rz[rowBase + ty * 4 + u];

    // running top-5 per row (only threads 0..63 use these meaningfully)
    float tv[5]; int ti[5];
    #pragma unroll
    for (int q = 0; q < 5; ++q) { tv[q] = NEG_INF; ti[q] = 0; }

    for (int chunk = split; chunk < nChunks; chunk += NSPLITS) {
        const int colBase = chunk * TN;
        float acc[4][8];
        #pragma unroll
        for (int u = 0; u < 4; ++u)
            #pragma unroll
            for (int v = 0; v < 8; ++v) acc[u][v] = 0.0f;

        const float* zp = z + (size_t)(rowBase + ar) * DDIM;
        const int bRow = colBase + br;
        const bool bvalid = bRow < N;
        const float* bp = bank + (size_t)(bvalid ? bRow : 0) * DDIM + bkg * 16;

        for (int ks = 0; ks < DDIM / KB; ++ks) {
            __syncthreads();   // previous FMA / scan reads of smem done
            const int k0 = ks * KB;
            float4 a0 = *(const float4*)(zp + k0 + akg * 4);
            float4 a1 = *(const float4*)(zp + k0 + 16 + akg * 4);
            float4 bq[4];
            #pragma unroll
            for (int q = 0; q < 4; ++q) {
                if (bvalid) bq[q] = *(const float4*)(bp + k0 + q * 4);
                else        bq[q] = make_float4(0.f, 0.f, 0.f, 0.f);
            }
            {   // transposed LDS writes (all 2-way bank aliasing = free)
                float av0[4], av1[4];
                *(float4*)av0 = a0; *(float4*)av1 = a1;
                #pragma unroll
                for (int j = 0; j < 4; ++j) {
                    LA[(akg * 4 + j) * LDA_PITCH + ar]      = av0[j];
                    LA[(16 + akg * 4 + j) * LDA_PITCH + ar] = av1[j];
                }
                float bvw[16];
                #pragma unroll
                for (int q = 0; q < 4; ++q) *(float4*)(bvw + 4 * q) = bq[q];
                #pragma unroll
                for (int q = 0; q < 4; ++q)
                    #pragma unroll
                    for (int j = 0; j < 4; ++j)
                        LB[(bkg * 16 + q * 4 + j) * LDB_PITCH + br] = bvw[q * 4 + j];
            }
            __syncthreads();
            #pragma unroll
            for (int kk = 0; kk < KB; ++kk) {
                float a[4], b[8];
                *(float4*)a       = *(const float4*)&LA[kk * LDA_PITCH + ty * 4];
                *(float4*)b       = *(const float4*)&LB[kk * LDB_PITCH + tx * 4];
                *(float4*)(b + 4) = *(const float4*)&LB[kk * LDB_PITCH + 64 + tx * 4];
                #pragma unroll
                for (int u = 0; u < 4; ++u)
                    #pragma unroll
                    for (int v = 0; v < 8; ++v)
                        acc[u][v] = fmaf(a[u], b[v], acc[u][v]);
            }
        }
        __syncthreads();       // last FMA reads done before SIM overwrites staging

        #pragma unroll
        for (int v = 0; v < 8; ++v) {
            const int c  = (v < 4) ? (tx * 4 + v) : (64 + tx * 4 + (v - 4));
            const int gc = colBase + c;
            const bool ok = gc < N;
            const float rbv = ok ? rb[gc] : 0.0f;
            #pragma unroll
            for (int u = 0; u < 4; ++u)
                SIM[(ty * 4 + u) * SIMS_PITCH + c] =
                    ok ? (acc[u][v] * rzv[u] * rbv) : NEG_INF;
        }
        __syncthreads();

        if (t < TM) {
            const int r = t;
            for (int c = 0; c < TN; ++c) {
                float v = SIM[r * SIMS_PITCH + c];
                if (v > tv[4]) {              // global idx strictly increases -> ties keep earlier
                    int q = 4;
                    while (q > 0 && v > tv[q - 1]) {
                        tv[q] = tv[q - 1]; ti[q] = ti[q - 1]; --q;
                    }
                    tv[q] = v; ti[q] = colBase + c;
                }
            }
        }
        // barrier at top of next chunk's ks-loop protects SIM from restaging
    }

    if (t < TM && (rowBase + t) < B) {
        size_t base = ((size_t)(rowBase + t) * NSPLITS + split) * 5;
        #pragma unroll
        for (int q = 0; q < 5; ++q) { cand_v[base + q] = tv[q]; cand_i[base + q] = ti[q]; }
    }
}

__global__ __launch_bounds__(64) void merge_topk_k(
    const float* __restrict__ cand_v, const int* __restrict__ cand_i,
    const int* __restrict__ labels, float* __restrict__ out, int BK) {
    const int row = blockIdx.x;
    const int lane = threadIdx.x;
    const int M = NSPLITS * 5;   // 320 candidates, all real (every split sees >=5 cols)

    float tv[5]; int ti[5];
    #pragma unroll
    for (int q = 0; q < 5; ++q) { tv[q] = NEG_INF; ti[q] = 0x7fffffff; }

    const size_t base = (size_t)row * M;
    for (int j = lane; j < M; j += 64) {
        float v = cand_v[base + j];
        int   i = cand_i[base + j];
        if (v > tv[4] || (v == tv[4] && i < ti[4])) {
            int q = 4;
            while (q > 0 && (v > tv[q - 1] || (v == tv[q - 1] && i < ti[q - 1]))) {
                tv[q] = tv[q - 1]; ti[q] = ti[q - 1]; --q;
            }
            tv[q] = v; ti[q] = i;
        }
    }

    for (int r = 0; r < 5; ++r) {
        float bv = tv[0]; int bi = ti[0];
        #pragma unroll
        for (int off = 32; off > 0; off >>= 1) {
            float ov = __shfl_xor(bv, off, 64);
            int   oi = __shfl_xor(bi, off, 64);
            if (ov > bv || (ov == bv && oi < bi)) { bv = ov; bi = oi; }
        }
        if (tv[0] == bv && ti[0] == bi) {   // unique winner: candidate idx are distinct
            #pragma unroll
            for (int q = 0; q < 4; ++q) { tv[q] = tv[q + 1]; ti[q] = ti[q + 1]; }
            tv[4] = NEG_INF; ti[4] = 0x7fffffff;
        }
        if (lane == 0) {
            out[(size_t)row * 5 + r]          = (float)bi;          // top_idx
            out[BK + (size_t)row * 5 + r]     = bv;                 // top_vals
            out[2 * BK + (size_t)row * 5 + r] = (float)labels[bi];  // labels
        }
    }
}

extern "C" void kernel_launch(void* const* d_in, const int* in_sizes, int n_in,
                              void* d_out, int out_size, void* d_ws, size_t ws_size,
                              hipStream_t stream) {
    const float* z    = (const float*)d_in[0];
    const float* bank = (const float*)d_in[1];
    const int*   lab  = (const int*)d_in[2];
    const int B = in_sizes[0] / DDIM;     // 1024
    const int N = in_sizes[1] / DDIM;     // 100000
    const int BK = out_size / 3;          // 5120
    const int nChunks = (N + TN - 1) / TN;
    float* out = (float*)d_out;

    char* ws = (char*)d_ws;
    float* rz = (float*)ws;                                   // B floats
    float* rb = (float*)(ws + 8192);                          // N floats
    size_t off = 8192 + (((size_t)N * 4 + 511) / 512) * 512;
    float* cand_v = (float*)(ws + off);                       // B*NSPLITS*5 floats
    int*   cand_i = (int*)(ws + off + (size_t)B * NSPLITS * 5 * 4);

    row_rnorm_k<<<(B + 3) / 4, 256, 0, stream>>>(z, rz, B);
    row_rnorm_k<<<(N + 3) / 4, 256, 0, stream>>>(bank, rb, N);
    gemm_topk_k<<<dim3(B / TM, NSPLITS), 256, 0, stream>>>(z, bank, rz, rb,
                                                           cand_v, cand_i, B, N, nChunks);
    merge_topk_k<<<B, 64, 0, stream>>>(cand_v, cand_i, lab, out, BK);
}

// Round 3
// 911.972 us; speedup vs baseline: 2.2573x; 2.2573x over previous
//
#include <hip/hip_runtime.h>
#include <math.h>

#define DDIM 512
#define TM 128
#define TN 128
#define NSPLITS 96
#define PITCH_I 20      // ints per f16-plane row = 40 halves (32 + 8 pad)
#define SIM_PITCH 67
#define NEG_INF (-3.0e38f)

typedef __fp16   h16x2 __attribute__((ext_vector_type(2)));   // cvt_pkrtz result type
typedef _Float16 f16x8 __attribute__((ext_vector_type(8)));
typedef float    f32x4 __attribute__((ext_vector_type(4)));
typedef int      i32x4 __attribute__((ext_vector_type(4)));

__global__ __launch_bounds__(256) void row_rnorm_k(const float* __restrict__ x,
                                                   float* __restrict__ rn, int rows) {
    int wave = threadIdx.x >> 6;
    int lane = threadIdx.x & 63;
    int row = blockIdx.x * 4 + wave;
    if (row >= rows) return;
    const float* p = x + (size_t)row * DDIM + lane * 4;
    float4 a = *(const float4*)p;
    float4 b = *(const float4*)(p + 256);
    float s = a.x*a.x + a.y*a.y + a.z*a.z + a.w*a.w
            + b.x*b.x + b.y*b.y + b.z*b.z + b.w*b.w;
    #pragma unroll
    for (int off = 32; off > 0; off >>= 1) s += __shfl_xor(s, off, 64);
    if (lane == 0) rn[row] = 1.0f / fmaxf(sqrtf(s), 1e-12f);
}

// split 16 floats into packed f16 hi/lo planes (8 ints each)
__device__ __forceinline__ void split16(const float* x, int* hi, int* lo) {
    #pragma unroll
    for (int p = 0; p < 8; ++p) {
        float x0 = x[2 * p], x1 = x[2 * p + 1];
        h16x2 h = __builtin_amdgcn_cvt_pkrtz(x0, x1);
        float r0 = x0 - (float)h.x;
        float r1 = x1 - (float)h.y;
        h16x2 l = __builtin_amdgcn_cvt_pkrtz(r0, r1);
        hi[p] = __builtin_bit_cast(int, h);
        lo[p] = __builtin_bit_cast(int, l);
    }
}

__global__ __launch_bounds__(256, 2) void gemm_topk_k(
    const float* __restrict__ z, const float* __restrict__ bank,
    const float* __restrict__ rb,
    float* __restrict__ cand_v, int* __restrict__ cand_i,
    int B, int N, int nChunks) {

    __shared__ int smem[10240];          // 40 KB
    int* AH = smem;                       // [128][PITCH_I]
    int* AL = smem + 2560;
    int* BH = smem + 5120;
    int* BL = smem + 7680;
    float* SIM = (float*)smem;            // [128][SIM_PITCH] fp32, aliased

    const int t    = threadIdx.x;
    const int wave = t >> 6, lane = t & 63;
    const int wm   = wave & 1, wn = wave >> 1;     // 2x2 wave grid over 128x128
    const int quad = lane >> 4, l16 = lane & 15;
    const int rowBase = blockIdx.x * TM;
    const int split   = blockIdx.y;

    const int srow = t >> 1;              // staging row 0..127
    const int skg  = (t & 1) * 8;         // int offset (8 ints = 16 halves)

    const float* zrow = z + (size_t)(rowBase + srow) * DDIM + (t & 1) * 16;

    float tv[5]; int ti[5];
    #pragma unroll
    for (int q = 0; q < 5; ++q) { tv[q] = NEG_INF; ti[q] = 0; }

    for (int chunk = split; chunk < nChunks; chunk += NSPLITS) {
        const int colBase = chunk * TN;
        const int bRow = colBase + srow;
        const bool bvalid = bRow < N;
        const float* brow = bank + (size_t)(bvalid ? bRow : 0) * DDIM + (t & 1) * 16;

        f32x4 acc[4][4];
        #pragma unroll
        for (int mi = 0; mi < 4; ++mi)
            #pragma unroll
            for (int ni = 0; ni < 4; ++ni)
                acc[mi][ni] = (f32x4){0.f, 0.f, 0.f, 0.f};

        for (int ks = 0; ks < DDIM / 32; ++ks) {
            const int k0 = ks * 32;
            float a[16], b[16];
            #pragma unroll
            for (int q = 0; q < 4; ++q)
                *(float4*)(a + 4 * q) = *(const float4*)(zrow + k0 + 4 * q);
            if (bvalid) {
                #pragma unroll
                for (int q = 0; q < 4; ++q)
                    *(float4*)(b + 4 * q) = *(const float4*)(brow + k0 + 4 * q);
            } else {
                #pragma unroll
                for (int j = 0; j < 16; ++j) b[j] = 0.f;
            }
            int ahi[8], alo[8], bhi[8], blo[8];
            split16(a, ahi, alo);
            split16(b, bhi, blo);

            __syncthreads();   // prior frag reads / SIM scan done
            {
                int o = srow * PITCH_I + skg;
                *(i32x4*)(AH + o) = *(i32x4*)(ahi); *(i32x4*)(AH + o + 4) = *(i32x4*)(ahi + 4);
                *(i32x4*)(AL + o) = *(i32x4*)(alo); *(i32x4*)(AL + o + 4) = *(i32x4*)(alo + 4);
                *(i32x4*)(BH + o) = *(i32x4*)(bhi); *(i32x4*)(BH + o + 4) = *(i32x4*)(bhi + 4);
                *(i32x4*)(BL + o) = *(i32x4*)(blo); *(i32x4*)(BL + o + 4) = *(i32x4*)(blo + 4);
            }
            __syncthreads();

            f16x8 ah[4], al[4], bh[4], bl[4];
            #pragma unroll
            for (int mi = 0; mi < 4; ++mi) {
                int o = (wm * 64 + mi * 16 + l16) * PITCH_I + quad * 4;
                ah[mi] = __builtin_bit_cast(f16x8, *(const i32x4*)(AH + o));
                al[mi] = __builtin_bit_cast(f16x8, *(const i32x4*)(AL + o));
            }
            #pragma unroll
            for (int ni = 0; ni < 4; ++ni) {
                int o = (wn * 64 + ni * 16 + l16) * PITCH_I + quad * 4;
                bh[ni] = __builtin_bit_cast(f16x8, *(const i32x4*)(BH + o));
                bl[ni] = __builtin_bit_cast(f16x8, *(const i32x4*)(BL + o));
            }
            #pragma unroll
            for (int mi = 0; mi < 4; ++mi)
                #pragma unroll
                for (int ni = 0; ni < 4; ++ni) {
                    acc[mi][ni] = __builtin_amdgcn_mfma_f32_16x16x32_f16(ah[mi], bh[ni], acc[mi][ni], 0, 0, 0);
                    acc[mi][ni] = __builtin_amdgcn_mfma_f32_16x16x32_f16(ah[mi], bl[ni], acc[mi][ni], 0, 0, 0);
                    acc[mi][ni] = __builtin_amdgcn_mfma_f32_16x16x32_f16(al[mi], bh[ni], acc[mi][ni], 0, 0, 0);
                }
        }

        // epilogue: two half-passes of 64 cols; rb applied pre-compare (rz is a
        // positive row-constant -> ordering-invariant, folded into merge kernel)
        #pragma unroll
        for (int p = 0; p < 2; ++p) {
            __syncthreads();   // frag reads (p=0) / scan reads (p=1) done
            #pragma unroll
            for (int nj = 0; nj < 2; ++nj) {
                const int ni = p * 2 + nj;
                const int gcol = colBase + wn * 64 + p * 32 + nj * 16 + l16;
                const bool ok = gcol < N;
                const float rbv = ok ? rb[gcol] : 0.f;
                #pragma unroll
                for (int mi = 0; mi < 4; ++mi) {
                    const int simrow = wm * 64 + mi * 16 + quad * 4;
                    #pragma unroll
                    for (int r = 0; r < 4; ++r)
                        SIM[(simrow + r) * SIM_PITCH + wn * 32 + nj * 16 + l16] =
                            ok ? acc[mi][ni][r] * rbv : NEG_INF;
                }
            }
            __syncthreads();
            const int row = t >> 1, h = t & 1;
            const float* s = SIM + row * SIM_PITCH + h * 32;
            const int gbase = colBase + h * 64 + p * 32;
            for (int c = 0; c < 32; ++c) {
                float v = s[c];
                if (v > tv[4]) {      // ascending idx scan: strict '>' keeps earliest on ties
                    int q = 4;
                    while (q > 0 && v > tv[q - 1]) {
                        tv[q] = tv[q - 1]; ti[q] = ti[q - 1]; --q;
                    }
                    tv[q] = v; ti[q] = gbase + c;
                }
            }
        }
    }

    {   // candidates: 2 lists per row per split
        const int row = t >> 1, h = t & 1;
        size_t base = (((size_t)(rowBase + row) * NSPLITS + split) * 2 + h) * 5;
        #pragma unroll
        for (int q = 0; q < 5; ++q) { cand_v[base + q] = tv[q]; cand_i[base + q] = ti[q]; }
    }
}

__global__ __launch_bounds__(64) void merge_topk_k(
    const float* __restrict__ cand_v, const int* __restrict__ cand_i,
    const int* __restrict__ labels, const float* __restrict__ rz,
    float* __restrict__ out, int BK, int M) {
    const int row = blockIdx.x;
    const int lane = threadIdx.x;

    float tv[5]; int ti[5];
    #pragma unroll
    for (int q = 0; q < 5; ++q) { tv[q] = NEG_INF; ti[q] = 0x7fffffff; }

    const size_t base = (size_t)row * M;
    for (int j = lane; j < M; j += 64) {
        float v = cand_v[base + j];
        int   i = cand_i[base + j];
        if (v > tv[4] || (v == tv[4] && i < ti[4])) {
            int q = 4;
            while (q > 0 && (v > tv[q - 1] || (v == tv[q - 1] && i < ti[q - 1]))) {
                tv[q] = tv[q - 1]; ti[q] = ti[q - 1]; --q;
            }
            tv[q] = v; ti[q] = i;
        }
    }

    const float rzv = rz[row];
    for (int r = 0; r < 5; ++r) {
        float bv = tv[0]; int bi = ti[0];
        #pragma unroll
        for (int off = 32; off > 0; off >>= 1) {
            float ov = __shfl_xor(bv, off, 64);
            int   oi = __shfl_xor(bi, off, 64);
            if (ov > bv || (ov == bv && oi < bi)) { bv = ov; bi = oi; }
        }
        if (tv[0] == bv && ti[0] == bi) {   // unique winner: candidate idx disjoint by construction
            #pragma unroll
            for (int q = 0; q < 4; ++q) { tv[q] = tv[q + 1]; ti[q] = ti[q + 1]; }
            tv[4] = NEG_INF; ti[4] = 0x7fffffff;
        }
        if (lane == 0) {
            out[(size_t)row * 5 + r]          = (float)bi;
            out[BK + (size_t)row * 5 + r]     = bv * rzv;
            out[2 * BK + (size_t)row * 5 + r] = (float)labels[bi];
        }
    }
}

extern "C" void kernel_launch(void* const* d_in, const int* in_sizes, int n_in,
                              void* d_out, int out_size, void* d_ws, size_t ws_size,
                              hipStream_t stream) {
    const float* z    = (const float*)d_in[0];
    const float* bank = (const float*)d_in[1];
    const int*   lab  = (const int*)d_in[2];
    const int B = in_sizes[0] / DDIM;     // 1024
    const int N = in_sizes[1] / DDIM;     // 100000
    const int BK = out_size / 3;          // 5120
    const int nChunks = (N + TN - 1) / TN;
    float* out = (float*)d_out;

    char* ws = (char*)d_ws;
    float* rz = (float*)ws;                                   // B floats
    float* rb = (float*)(ws + 8192);                          // N floats
    size_t off = 8192 + (((size_t)N * 4 + 511) / 512) * 512;
    const size_t ncand = (size_t)B * NSPLITS * 2 * 5;
    float* cand_v = (float*)(ws + off);
    int*   cand_i = (int*)(ws + off + ncand * 4);

    row_rnorm_k<<<(B + 3) / 4, 256, 0, stream>>>(z, rz, B);
    row_rnorm_k<<<(N + 3) / 4, 256, 0, stream>>>(bank, rb, N);
    gemm_topk_k<<<dim3(B / TM, NSPLITS), 256, 0, stream>>>(z, bank, rb,
                                                           cand_v, cand_i, B, N, nChunks);
    merge_topk_k<<<B, 64, 0, stream>>>(cand_v, cand_i, lab, rz, out, BK, NSPLITS * 2 * 5);
}

// Round 4
// 755.470 us; speedup vs baseline: 2.7249x; 1.2072x over previous
//
#include <hip/hip_runtime.h>
#include <math.h>

#define DDIM 512
#define NEG_INF (-3.0e38f)
#define IMAX 0x7fffffff

typedef __fp16   h16x2 __attribute__((ext_vector_type(2)));   // cvt_pkrtz result type
typedef _Float16 f16x8 __attribute__((ext_vector_type(8)));
typedef float    f32x4 __attribute__((ext_vector_type(4)));
typedef int      i32x4 __attribute__((ext_vector_type(4)));

__device__ __forceinline__ void glds16(const void* g, void* l) {
    __builtin_amdgcn_global_load_lds((const __attribute__((address_space(1))) void*)g,
                                     (__attribute__((address_space(3))) void*)l, 16, 0, 0);
}

// ---------------- main path ----------------

// fp32 rows -> f16 tile [chunk][ks 16][128 rows][32 halves] + reciprocal norms
__global__ __launch_bounds__(256) void split_tile_k(const float* __restrict__ src,
                                                    unsigned* __restrict__ tile,
                                                    float* __restrict__ rn, int rows) {
    const int t = threadIdx.x;
    const int l16 = t & 15, rloc = t >> 4;
    const int R = blockIdx.x * 16 + rloc;
    if (R >= rows) return;
    const int chunk = R >> 7, r = R & 127;
    const float* srow = src + (size_t)R * DDIM;
    float ss = 0.f;
    #pragma unroll
    for (int it = 0; it < 8; ++it) {
        const int c = it * 64 + l16 * 4;
        float4 v = *(const float4*)(srow + c);
        ss += v.x*v.x + v.y*v.y + v.z*v.z + v.w*v.w;
        h16x2 p0 = __builtin_amdgcn_cvt_pkrtz(v.x, v.y);
        h16x2 p1 = __builtin_amdgcn_cvt_pkrtz(v.z, v.w);
        const int ks = it * 2 + (l16 >> 3);
        unsigned* dst = tile + ((size_t)(chunk * 16 + ks) * 128 + r) * 16 + (l16 & 7) * 2;
        dst[0] = __builtin_bit_cast(unsigned, p0);
        dst[1] = __builtin_bit_cast(unsigned, p1);
    }
    ss += __shfl_xor(ss, 1, 64); ss += __shfl_xor(ss, 2, 64);
    ss += __shfl_xor(ss, 4, 64); ss += __shfl_xor(ss, 8, 64);
    if (l16 == 0) rn[R] = 1.0f / fmaxf(sqrtf(ss), 1e-12f);
}

// f16 screen GEMM (128x128 tile, glds staging) + per-half-thread top-8
__global__ __launch_bounds__(256, 2) void gemm_screen_k(
    const unsigned* __restrict__ zh, const unsigned* __restrict__ bh,
    const float* __restrict__ rb,
    float* __restrict__ cand_v, int* __restrict__ cand_i,
    int N, int nChunks, int nSplits) {

    __shared__ alignas(16) char smem[33280];          // 16KB staging | 128x65 f32 SIM (aliased)
    float* SIM = (float*)smem;

    const int t = threadIdx.x;
    const int w = t >> 6, lane = t & 63;
    const int wm = w & 1, wn = w >> 1;
    const int quad = lane >> 4, l16 = lane & 15;
    const int rowblk = blockIdx.x, split = blockIdx.y;
    const int soff = w * 1024 + lane * 16;            // byte offset within a 4KB slab

    float tv[8]; int ti[8];
    #pragma unroll
    for (int q = 0; q < 8; ++q) { tv[q] = NEG_INF; ti[q] = 0; }

    for (int chunk = split; chunk < nChunks; chunk += nSplits) {
        f32x4 acc[4][4];
        #pragma unroll
        for (int mi = 0; mi < 4; ++mi)
            #pragma unroll
            for (int ni = 0; ni < 4; ++ni) acc[mi][ni] = (f32x4){0.f, 0.f, 0.f, 0.f};

        for (int ks = 0; ks < 16; ++ks) {
            __syncthreads();   // prior frag/scan reads of smem done
            const char* gA = (const char*)zh + ((size_t)(rowblk * 16 + ks) * 8192);
            const char* gB = (const char*)bh + ((size_t)(chunk * 16 + ks) * 8192);
            glds16(gA + soff,        smem + soff);
            glds16(gA + 4096 + soff, smem + 4096 + soff);
            glds16(gB + soff,        smem + 8192 + soff);
            glds16(gB + 4096 + soff, smem + 12288 + soff);
            __syncthreads();   // barrier drains vmcnt -> LDS deposits visible

            const unsigned short* A  = (const unsigned short*)smem;
            const unsigned short* Bb = (const unsigned short*)(smem + 8192);
            f16x8 af[4], bf[4];
            #pragma unroll
            for (int mi = 0; mi < 4; ++mi)
                af[mi] = __builtin_bit_cast(f16x8,
                    *(const i32x4*)(A + (wm * 64 + mi * 16 + l16) * 32 + quad * 8));
            #pragma unroll
            for (int ni = 0; ni < 4; ++ni)
                bf[ni] = __builtin_bit_cast(f16x8,
                    *(const i32x4*)(Bb + (wn * 64 + ni * 16 + l16) * 32 + quad * 8));
            #pragma unroll
            for (int mi = 0; mi < 4; ++mi)
                #pragma unroll
                for (int ni = 0; ni < 4; ++ni)
                    acc[mi][ni] = __builtin_amdgcn_mfma_f32_16x16x32_f16(af[mi], bf[ni], acc[mi][ni], 0, 0, 0);
        }

        // epilogue: 2 passes x 64 cols; rb applied pre-compare (rz row-constant)
        #pragma unroll
        for (int p = 0; p < 2; ++p) {
            __syncthreads();
            #pragma unroll
            for (int nj = 0; nj < 2; ++nj) {
                const int ni = p * 2 + nj;
                const int gcol = chunk * 128 + wn * 64 + p * 32 + nj * 16 + l16;
                const bool ok = gcol < N;
                const float rbv = ok ? rb[gcol] : 0.f;
                #pragma unroll
                for (int mi = 0; mi < 4; ++mi) {
                    const int srow = wm * 64 + mi * 16 + quad * 4;
                    #pragma unroll
                    for (int r = 0; r < 4; ++r)
                        SIM[(srow + r) * 65 + wn * 32 + nj * 16 + l16] =
                            ok ? acc[mi][ni][r] * rbv : NEG_INF;
                }
            }
            __syncthreads();
            const int sr = t >> 1, h = t & 1;
            const float* s = SIM + sr * 65 + h * 32;
            const int gbase = chunk * 128 + h * 64 + p * 32;
            for (int c = 0; c < 32; ++c) {
                float v = s[c];
                if (v > tv[7]) {
                    int q = 7;
                    while (q > 0 && v > tv[q - 1]) { tv[q] = tv[q - 1]; ti[q] = ti[q - 1]; --q; }
                    tv[q] = v; ti[q] = gbase + c;
                }
            }
        }
    }

    const int sr = t >> 1, h = t & 1;
    size_t base = (((size_t)(rowblk * 128 + sr) * nSplits + split) * 2 + h) * 8;
    #pragma unroll
    for (int q = 0; q < 8; ++q) { cand_v[base + q] = tv[q]; cand_i[base + q] = ti[q]; }
}

// per row: merge 1024 approx candidates -> top-32, exact fp32 rescore, final top-5
__global__ __launch_bounds__(256) void merge_rescore_k(
    const float* __restrict__ cand_v, const int* __restrict__ cand_i,
    const float* __restrict__ z, const float* __restrict__ bank,
    const float* __restrict__ rz, const float* __restrict__ rb,
    const int* __restrict__ labels, float* __restrict__ out, int BK, int N) {

    __shared__ float zrow[DDIM];
    __shared__ int   idxs[32];
    __shared__ float dots[32];

    const int row = blockIdx.x;
    const int t = threadIdx.x, w = t >> 6, lane = t & 63;

    {   float2 v = *(const float2*)(z + (size_t)row * DDIM + t * 2);
        zrow[t * 2] = v.x; zrow[t * 2 + 1] = v.y; }

    if (w == 0) {
        float sv[16]; int si[16];
        const size_t base = (size_t)row * 1024;
        #pragma unroll
        for (int q = 0; q < 16; ++q) {
            sv[q] = cand_v[base + lane * 16 + q];
            si[q] = cand_i[base + lane * 16 + q];
        }
        // in-register bitonic sort, descending (static indices)
        #pragma unroll
        for (int k = 2; k <= 16; k <<= 1)
            #pragma unroll
            for (int j = k >> 1; j > 0; j >>= 1)
                #pragma unroll
                for (int i = 0; i < 16; ++i) {
                    const int l = i ^ j;
                    if (l > i) {
                        const bool dir = ((i & k) == 0);   // desc overall
                        bool sw = dir ? (sv[i] < sv[l]) : (sv[i] > sv[l]);
                        float fv = sw ? sv[l] : sv[i]; float fw = sw ? sv[i] : sv[l];
                        int   gv = sw ? si[l] : si[i]; int   gw = sw ? si[i] : si[l];
                        sv[i] = fv; sv[l] = fw; si[i] = gv; si[l] = gw;
                    }
                }
        // pop-32 with shift (candidate idx are globally distinct)
        for (int r = 0; r < 32; ++r) {
            float bv = sv[0]; int bi = si[0];
            #pragma unroll
            for (int off = 32; off > 0; off >>= 1) {
                float ov = __shfl_xor(bv, off, 64);
                int   oi = __shfl_xor(bi, off, 64);
                if (ov > bv || (ov == bv && oi < bi)) { bv = ov; bi = oi; }
            }
            if (sv[0] == bv && si[0] == bi) {
                #pragma unroll
                for (int q = 0; q < 15; ++q) { sv[q] = sv[q + 1]; si[q] = si[q + 1]; }
                sv[15] = NEG_INF; si[15] = IMAX;
            }
            if (lane == 0) idxs[r] = bi;
        }
    }
    __syncthreads();

    // rescore: wave w handles candidates w*8 .. w*8+7 (exact fp32 raw dot)
    #pragma unroll
    for (int jj = 0; jj < 8; ++jj) {
        const int ci = idxs[w * 8 + jj];
        const float* br = bank + (size_t)ci * DDIM + lane * 8;
        float4 x0 = *(const float4*)br;
        float4 x1 = *(const float4*)(br + 4);
        const float* zz = zrow + lane * 8;
        float4 z0 = *(const float4*)zz;
        float4 z1 = *(const float4*)(zz + 4);
        float s = x0.x*z0.x + x0.y*z0.y + x0.z*z0.z + x0.w*z0.w
                + x1.x*z1.x + x1.y*z1.y + x1.z*z1.z + x1.w*z1.w;
        #pragma unroll
        for (int off = 32; off > 0; off >>= 1) s += __shfl_xor(s, off, 64);
        if (lane == 0) dots[w * 8 + jj] = s;
    }
    __syncthreads();

    if (w == 0) {
        const float rzv = rz[row];
        float v; int ii;
        if (lane < 32) { ii = idxs[lane]; v = dots[lane] * rzv * rb[ii]; }
        else           { ii = IMAX;       v = NEG_INF; }
        for (int r = 0; r < 5; ++r) {
            float bv = v; int bi = ii;
            #pragma unroll
            for (int off = 32; off > 0; off >>= 1) {
                float ov = __shfl_xor(bv, off, 64);
                int   oi = __shfl_xor(bi, off, 64);
                if (ov > bv || (ov == bv && oi < bi)) { bv = ov; bi = oi; }
            }
            if (v == bv && ii == bi) { v = NEG_INF; ii = IMAX; }
            if (lane == 0) {
                out[(size_t)row * 5 + r]          = (float)bi;
                out[BK + (size_t)row * 5 + r]     = bv;
                out[2 * BK + (size_t)row * 5 + r] = (float)labels[bi];
            }
        }
    }
}

// ---------------- fallback path (R3, proven) ----------------

__global__ __launch_bounds__(256) void row_rnorm_k(const float* __restrict__ x,
                                                   float* __restrict__ rn, int rows) {
    int wave = threadIdx.x >> 6;
    int lane = threadIdx.x & 63;
    int row = blockIdx.x * 4 + wave;
    if (row >= rows) return;
    const float* p = x + (size_t)row * DDIM + lane * 4;
    float4 a = *(const float4*)p;
    float4 b = *(const float4*)(p + 256);
    float s = a.x*a.x + a.y*a.y + a.z*a.z + a.w*a.w
            + b.x*b.x + b.y*b.y + b.z*b.z + b.w*b.w;
    #pragma unroll
    for (int off = 32; off > 0; off >>= 1) s += __shfl_xor(s, off, 64);
    if (lane == 0) rn[row] = 1.0f / fmaxf(sqrtf(s), 1e-12f);
}

__device__ __forceinline__ void split16(const float* x, int* hi, int* lo) {
    #pragma unroll
    for (int p = 0; p < 8; ++p) {
        float x0 = x[2 * p], x1 = x[2 * p + 1];
        h16x2 h = __builtin_amdgcn_cvt_pkrtz(x0, x1);
        float r0 = x0 - (float)h.x;
        float r1 = x1 - (float)h.y;
        h16x2 l = __builtin_amdgcn_cvt_pkrtz(r0, r1);
        hi[p] = __builtin_bit_cast(int, h);
        lo[p] = __builtin_bit_cast(int, l);
    }
}

#define FB_PI 20
#define FB_SP 67

__global__ __launch_bounds__(256, 2) void gemm_topk_fb(
    const float* __restrict__ z, const float* __restrict__ bank,
    const float* __restrict__ rb,
    float* __restrict__ cand_v, int* __restrict__ cand_i,
    int B, int N, int nChunks, int nSplits) {
    __shared__ int smem[10240];
    int* AH = smem; int* AL = smem + 2560; int* BH = smem + 5120; int* BL = smem + 7680;
    float* SIM = (float*)smem;
    const int t = threadIdx.x;
    const int wave = t >> 6, lane = t & 63;
    const int wm = wave & 1, wn = wave >> 1;
    const int quad = lane >> 4, l16 = lane & 15;
    const int rowBase = blockIdx.x * 128;
    const int split = blockIdx.y;
    const int srow = t >> 1;
    const int skg = (t & 1) * 8;
    const float* zrow = z + (size_t)(rowBase + srow) * DDIM + (t & 1) * 16;
    float tv[5]; int ti[5];
    #pragma unroll
    for (int q = 0; q < 5; ++q) { tv[q] = NEG_INF; ti[q] = 0; }
    for (int chunk = split; chunk < nChunks; chunk += nSplits) {
        const int colBase = chunk * 128;
        const int bRow = colBase + srow;
        const bool bvalid = bRow < N;
        const float* brow = bank + (size_t)(bvalid ? bRow : 0) * DDIM + (t & 1) * 16;
        f32x4 acc[4][4];
        #pragma unroll
        for (int mi = 0; mi < 4; ++mi)
            #pragma unroll
            for (int ni = 0; ni < 4; ++ni) acc[mi][ni] = (f32x4){0.f,0.f,0.f,0.f};
        for (int ks = 0; ks < 16; ++ks) {
            const int k0 = ks * 32;
            float a[16], b[16];
            #pragma unroll
            for (int q = 0; q < 4; ++q) *(float4*)(a + 4*q) = *(const float4*)(zrow + k0 + 4*q);
            if (bvalid) {
                #pragma unroll
                for (int q = 0; q < 4; ++q) *(float4*)(b + 4*q) = *(const float4*)(brow + k0 + 4*q);
            } else {
                #pragma unroll
                for (int j = 0; j < 16; ++j) b[j] = 0.f;
            }
            int ahi[8], alo[8], bhi[8], blo[8];
            split16(a, ahi, alo); split16(b, bhi, blo);
            __syncthreads();
            {
                int o = srow * FB_PI + skg;
                *(i32x4*)(AH+o) = *(i32x4*)ahi; *(i32x4*)(AH+o+4) = *(i32x4*)(ahi+4);
                *(i32x4*)(AL+o) = *(i32x4*)alo; *(i32x4*)(AL+o+4) = *(i32x4*)(alo+4);
                *(i32x4*)(BH+o) = *(i32x4*)bhi; *(i32x4*)(BH+o+4) = *(i32x4*)(bhi+4);
                *(i32x4*)(BL+o) = *(i32x4*)blo; *(i32x4*)(BL+o+4) = *(i32x4*)(blo+4);
            }
            __syncthreads();
            f16x8 ah[4], al[4], bh[4], bl[4];
            #pragma unroll
            for (int mi = 0; mi < 4; ++mi) {
                int o = (wm*64 + mi*16 + l16) * FB_PI + quad*4;
                ah[mi] = __builtin_bit_cast(f16x8, *(const i32x4*)(AH + o));
                al[mi] = __builtin_bit_cast(f16x8, *(const i32x4*)(AL + o));
            }
            #pragma unroll
            for (int ni = 0; ni < 4; ++ni) {
                int o = (wn*64 + ni*16 + l16) * FB_PI + quad*4;
                bh[ni] = __builtin_bit_cast(f16x8, *(const i32x4*)(BH + o));
                bl[ni] = __builtin_bit_cast(f16x8, *(const i32x4*)(BL + o));
            }
            #pragma unroll
            for (int mi = 0; mi < 4; ++mi)
                #pragma unroll
                for (int ni = 0; ni < 4; ++ni) {
                    acc[mi][ni] = __builtin_amdgcn_mfma_f32_16x16x32_f16(ah[mi], bh[ni], acc[mi][ni], 0,0,0);
                    acc[mi][ni] = __builtin_amdgcn_mfma_f32_16x16x32_f16(ah[mi], bl[ni], acc[mi][ni], 0,0,0);
                    acc[mi][ni] = __builtin_amdgcn_mfma_f32_16x16x32_f16(al[mi], bh[ni], acc[mi][ni], 0,0,0);
                }
        }
        #pragma unroll
        for (int p = 0; p < 2; ++p) {
            __syncthreads();
            #pragma unroll
            for (int nj = 0; nj < 2; ++nj) {
                const int ni = p*2 + nj;
                const int gcol = colBase + wn*64 + p*32 + nj*16 + l16;
                const bool ok = gcol < N;
                const float rbv = ok ? rb[gcol] : 0.f;
                #pragma unroll
                for (int mi = 0; mi < 4; ++mi) {
                    const int srw = wm*64 + mi*16 + quad*4;
                    #pragma unroll
                    for (int r = 0; r < 4; ++r)
                        SIM[(srw + r)*FB_SP + wn*32 + nj*16 + l16] = ok ? acc[mi][ni][r]*rbv : NEG_INF;
                }
            }
            __syncthreads();
            const int rr = t >> 1, h = t & 1;
            const float* s = SIM + rr*FB_SP + h*32;
            const int gbase = colBase + h*64 + p*32;
            for (int c = 0; c < 32; ++c) {
                float v = s[c];
                if (v > tv[4]) {
                    int q = 4;
                    while (q > 0 && v > tv[q-1]) { tv[q]=tv[q-1]; ti[q]=ti[q-1]; --q; }
                    tv[q] = v; ti[q] = gbase + c;
                }
            }
        }
    }
    {
        const int rr = t >> 1, h = t & 1;
        size_t base = (((size_t)(rowBase + rr) * nSplits + split) * 2 + h) * 5;
        #pragma unroll
        for (int q = 0; q < 5; ++q) { cand_v[base + q] = tv[q]; cand_i[base + q] = ti[q]; }
    }
}

__global__ __launch_bounds__(64) void merge_topk_fb(
    const float* __restrict__ cand_v, const int* __restrict__ cand_i,
    const int* __restrict__ labels, const float* __restrict__ rz,
    float* __restrict__ out, int BK, int M) {
    const int row = blockIdx.x;
    const int lane = threadIdx.x;
    float tv[5]; int ti[5];
    #pragma unroll
    for (int q = 0; q < 5; ++q) { tv[q] = NEG_INF; ti[q] = IMAX; }
    const size_t base = (size_t)row * M;
    for (int j = lane; j < M; j += 64) {
        float v = cand_v[base + j];
        int   i = cand_i[base + j];
        if (v > tv[4] || (v == tv[4] && i < ti[4])) {
            int q = 4;
            while (q > 0 && (v > tv[q-1] || (v == tv[q-1] && i < ti[q-1]))) {
                tv[q]=tv[q-1]; ti[q]=ti[q-1]; --q;
            }
            tv[q] = v; ti[q] = i;
        }
    }
    const float rzv = rz[row];
    for (int r = 0; r < 5; ++r) {
        float bv = tv[0]; int bi = ti[0];
        #pragma unroll
        for (int off = 32; off > 0; off >>= 1) {
            float ov = __shfl_xor(bv, off, 64);
            int   oi = __shfl_xor(bi, off, 64);
            if (ov > bv || (ov == bv && oi < bi)) { bv = ov; bi = oi; }
        }
        if (tv[0] == bv && ti[0] == bi) {
            #pragma unroll
            for (int q = 0; q < 4; ++q) { tv[q] = tv[q+1]; ti[q] = ti[q+1]; }
            tv[4] = NEG_INF; ti[4] = IMAX;
        }
        if (lane == 0) {
            out[(size_t)row * 5 + r]          = (float)bi;
            out[BK + (size_t)row * 5 + r]     = bv * rzv;
            out[2 * BK + (size_t)row * 5 + r] = (float)labels[bi];
        }
    }
}

// ---------------- launch ----------------

extern "C" void kernel_launch(void* const* d_in, const int* in_sizes, int n_in,
                              void* d_out, int out_size, void* d_ws, size_t ws_size,
                              hipStream_t stream) {
    const float* z    = (const float*)d_in[0];
    const float* bank = (const float*)d_in[1];
    const int*   lab  = (const int*)d_in[2];
    const int B = in_sizes[0] / DDIM;     // 1024
    const int N = in_sizes[1] / DDIM;     // 100000
    const int BK = out_size / 3;          // 5120
    const int nChunks = (N + 127) >> 7;   // 782
    float* out = (float*)d_out;
    char* ws = (char*)d_ws;

    const int NS = 64;
    const size_t o_rz = 0;
    const size_t o_rb = ((size_t)B * 4 + 511) / 512 * 512;                       // 4096
    const size_t o_zh = o_rb + ((size_t)nChunks * 128 * 4 + 511) / 512 * 512;    // rb region
    const size_t o_bh = o_zh + (size_t)(B / 128) * 16 * 128 * 64;                // zh tile (1 MB)
    const size_t o_cv = o_bh + (size_t)nChunks * 16 * 128 * 64;                  // bh tile
    const size_t szC  = (size_t)B * NS * 2 * 8 * 4;
    const size_t o_ci = o_cv + szC;
    const size_t need = o_ci + szC;

    if (ws_size >= need) {
        float* rz = (float*)(ws + o_rz);
        float* rb = (float*)(ws + o_rb);
        unsigned* zh = (unsigned*)(ws + o_zh);
        unsigned* bh = (unsigned*)(ws + o_bh);
        float* cand_v = (float*)(ws + o_cv);
        int*   cand_i = (int*)(ws + o_ci);

        split_tile_k<<<(N + 15) / 16, 256, 0, stream>>>(bank, bh, rb, N);
        split_tile_k<<<(B + 15) / 16, 256, 0, stream>>>(z, zh, rz, B);
        gemm_screen_k<<<dim3(B / 128, NS), 256, 0, stream>>>(zh, bh, rb, cand_v, cand_i,
                                                             N, nChunks, NS);
        merge_rescore_k<<<B, 256, 0, stream>>>(cand_v, cand_i, z, bank, rz, rb, lab,
                                               out, BK, N);
    } else {
        // fallback: R3 proven path (~8.3 MB ws)
        const int NSF = 96;
        float* rz = (float*)ws;
        float* rb = (float*)(ws + 8192);
        size_t off = 8192 + (((size_t)N * 4 + 511) / 512) * 512;
        const size_t ncand = (size_t)B * NSF * 2 * 5;
        float* cand_v = (float*)(ws + off);
        int*   cand_i = (int*)(ws + off + ncand * 4);
        row_rnorm_k<<<(B + 3) / 4, 256, 0, stream>>>(z, rz, B);
        row_rnorm_k<<<(N + 3) / 4, 256, 0, stream>>>(bank, rb, N);
        gemm_topk_fb<<<dim3(B / 128, NSF), 256, 0, stream>>>(z, bank, rb, cand_v, cand_i,
                                                             B, N, nChunks, NSF);
        merge_topk_fb<<<B, 64, 0, stream>>>(cand_v, cand_i, lab, rz, out, BK, NSF * 2 * 5);
    }
}

// Round 5
// 547.526 us; speedup vs baseline: 3.7598x; 1.3798x over previous
//
#include <hip/hip_runtime.h>
#include <math.h>

#define DDIM 512
#define NS 96
#define SPITCH 132
#define KMASK 0xFFFFF800
#define NEG_INF (-3.0e38f)
#define IMAX 0x7fffffff

typedef __fp16   h16x2 __attribute__((ext_vector_type(2)));
typedef _Float16 f16x8 __attribute__((ext_vector_type(8)));
typedef float    f32x4 __attribute__((ext_vector_type(4)));
typedef int      i32x4 __attribute__((ext_vector_type(4)));

__device__ __forceinline__ int imin(int a, int b) { return a < b ? a : b; }
__device__ __forceinline__ int imax(int a, int b) { return a > b ? a : b; }

__device__ __forceinline__ void glds16(const void* g, void* l) {
    __builtin_amdgcn_global_load_lds((const __attribute__((address_space(1))) void*)g,
                                     (__attribute__((address_space(3))) void*)l, 16, 0, 0);
}

// fp32 rows -> f16 tile [chunk*16+ks][128 rows][32 halves] + reciprocal norms.
// thread = (row r = t>>1, half hf = t&1): stores are perfectly coalesced dwordx4;
// read pairs (hf=0/1) cover one 128-B line.
__global__ __launch_bounds__(256) void split_tile_k(const float* __restrict__ src,
                                                    unsigned* __restrict__ tile,
                                                    float* __restrict__ rn, int rows) {
    const int t = threadIdx.x;
    const int r = t >> 1, hf = t & 1;
    const int R = blockIdx.x * 128 + r;
    const bool valid = R < rows;
    const float* srow = src + (size_t)(valid ? R : 0) * DDIM + hf * 16;
    float ss = 0.f;
    for (int ks = 0; ks < 16; ++ks) {
        float4 v0 = *(const float4*)(srow + ks * 32);
        float4 v1 = *(const float4*)(srow + ks * 32 + 4);
        float4 v2 = *(const float4*)(srow + ks * 32 + 8);
        float4 v3 = *(const float4*)(srow + ks * 32 + 12);
        ss += v0.x*v0.x + v0.y*v0.y + v0.z*v0.z + v0.w*v0.w
            + v1.x*v1.x + v1.y*v1.y + v1.z*v1.z + v1.w*v1.w
            + v2.x*v2.x + v2.y*v2.y + v2.z*v2.z + v2.w*v2.w
            + v3.x*v3.x + v3.y*v3.y + v3.z*v3.z + v3.w*v3.w;
        unsigned o[8];
        o[0] = __builtin_bit_cast(unsigned, __builtin_amdgcn_cvt_pkrtz(v0.x, v0.y));
        o[1] = __builtin_bit_cast(unsigned, __builtin_amdgcn_cvt_pkrtz(v0.z, v0.w));
        o[2] = __builtin_bit_cast(unsigned, __builtin_amdgcn_cvt_pkrtz(v1.x, v1.y));
        o[3] = __builtin_bit_cast(unsigned, __builtin_amdgcn_cvt_pkrtz(v1.z, v1.w));
        o[4] = __builtin_bit_cast(unsigned, __builtin_amdgcn_cvt_pkrtz(v2.x, v2.y));
        o[5] = __builtin_bit_cast(unsigned, __builtin_amdgcn_cvt_pkrtz(v2.z, v2.w));
        o[6] = __builtin_bit_cast(unsigned, __builtin_amdgcn_cvt_pkrtz(v3.x, v3.y));
        o[7] = __builtin_bit_cast(unsigned, __builtin_amdgcn_cvt_pkrtz(v3.z, v3.w));
        if (!valid) {
            #pragma unroll
            for (int q = 0; q < 8; ++q) o[q] = 0u;   // zero-pad OOB bank rows
        }
        unsigned* dst = tile + ((size_t)(blockIdx.x * 16 + ks) * 128 + r) * 16 + hf * 8;
        *(i32x4*)dst       = *(i32x4*)o;
        *(i32x4*)(dst + 4) = *(i32x4*)(o + 4);
    }
    ss += __shfl_xor(ss, 1, 64);
    if (valid && hf == 0) rn[R] = 1.0f / fmaxf(sqrtf(ss), 1e-12f);
}

// f16 screen GEMM (128x128 tile, glds staging) + branchless packed-key top-4
// per (row, 64-col half, split). key = (simbits & KMASK) | iter<<7 | col7.
__global__ __launch_bounds__(256, 3) void gemm_screen_k(
    const unsigned* __restrict__ zh, const unsigned* __restrict__ bh,
    const float* __restrict__ rb,
    int* __restrict__ cand, int N, int nChunks) {

    __shared__ alignas(16) int smem[8448];   // 33792 B: 16KB staging | 64 x SPITCH key SIM (aliased)
    int* SIMI = smem;

    const int t = threadIdx.x;
    const int w = t >> 6, lane = t & 63;
    const int wm = w & 1, wn = w >> 1;
    const int quad = lane >> 4, l16 = lane & 15;
    const int split = blockIdx.x, rowblk = blockIdx.y;  // 8 rowblks of a split share one XCD
    const int soff = w * 1024 + lane * 16;

    int t0 = (int)0x80000000, t1 = t0, t2 = t0, t3 = t0;

    int iter = 0;
    for (int chunk = split; chunk < nChunks; chunk += NS, ++iter) {
        f32x4 acc[4][4];
        #pragma unroll
        for (int mi = 0; mi < 4; ++mi)
            #pragma unroll
            for (int ni = 0; ni < 4; ++ni) acc[mi][ni] = (f32x4){0.f, 0.f, 0.f, 0.f};

        for (int ks = 0; ks < 16; ++ks) {
            __syncthreads();   // prior frag/scan reads of smem done
            const char* gA = (const char*)zh + ((size_t)(rowblk * 16 + ks) * 8192);
            const char* gB = (const char*)bh + ((size_t)(chunk * 16 + ks) * 8192);
            glds16(gA + soff,        (char*)smem + soff);
            glds16(gA + 4096 + soff, (char*)smem + 4096 + soff);
            glds16(gB + soff,        (char*)smem + 8192 + soff);
            glds16(gB + 4096 + soff, (char*)smem + 12288 + soff);
            __syncthreads();

            const unsigned short* A  = (const unsigned short*)smem;
            const unsigned short* Bb = (const unsigned short*)((char*)smem + 8192);
            f16x8 af[4], bf[4];
            #pragma unroll
            for (int mi = 0; mi < 4; ++mi)
                af[mi] = __builtin_bit_cast(f16x8,
                    *(const i32x4*)(A + (wm * 64 + mi * 16 + l16) * 32 + quad * 8));
            #pragma unroll
            for (int ni = 0; ni < 4; ++ni)
                bf[ni] = __builtin_bit_cast(f16x8,
                    *(const i32x4*)(Bb + (wn * 64 + ni * 16 + l16) * 32 + quad * 8));
            #pragma unroll
            for (int mi = 0; mi < 4; ++mi)
                #pragma unroll
                for (int ni = 0; ni < 4; ++ni)
                    acc[mi][ni] = __builtin_amdgcn_mfma_f32_16x16x32_f16(af[mi], bf[ni], acc[mi][ni], 0, 0, 0);
        }

        // epilogue: 2 passes x 64 cols, column-major key-SIM, branchless top-4 chain
        const int colBase = chunk * 128;
        const int iterTag = iter << 7;
        #pragma unroll
        for (int p = 0; p < 2; ++p) {
            __syncthreads();
            #pragma unroll
            for (int nj = 0; nj < 2; ++nj) {
                const int ni = p * 2 + nj;
                const int cCol = wn * 64 + ni * 16 + l16;       // col-in-chunk, 7 bits
                const float rbv = rb[colBase + cCol];            // OOB-safe: rb sized 100096
                const int cp = wn * 32 + nj * 16 + l16;          // col slot in this pass
                #pragma unroll
                for (int mi = 0; mi < 4; ++mi) {
                    i32x4 kv;
                    #pragma unroll
                    for (int rr = 0; rr < 4; ++rr) {
                        float v = acc[mi][ni][rr] * rbv;
                        kv[rr] = (__float_as_int(v) & KMASK) | cCol;
                    }
                    *(i32x4*)(SIMI + cp * SPITCH + wm * 64 + mi * 16 + quad * 4) = kv;
                }
            }
            __syncthreads();
            {
                const int r = t >> 1, h = t & 1;
                const int* s = SIMI + (h * 32) * SPITCH + r;
                #pragma unroll
                for (int j = 0; j < 32; ++j) {
                    int kk = s[j * SPITCH] | iterTag;
                    int k1 = imin(kk, t0); t0 = imax(kk, t0);
                    int k2 = imin(k1, t1); t1 = imax(k1, t1);
                    int k3 = imin(k2, t2); t2 = imax(k2, t2);
                    t3 = imax(k3, t3);
                }
            }
        }
    }

    const int r = t >> 1, h = t & 1;
    i32x4 outk = { t0, t1, t2, t3 };
    *(i32x4*)(cand + (((size_t)(rowblk * 128 + r) * NS + split) * 2 + h) * 4) = outk;
}

// per row: pop exact top-32 of 768 packed keys, exact fp32 rescore, final top-5
__global__ __launch_bounds__(256) void merge_rescore_k(
    const int* __restrict__ cand,
    const float* __restrict__ z, const float* __restrict__ bank,
    const float* __restrict__ rz, const float* __restrict__ rb,
    const int* __restrict__ labels, float* __restrict__ out, int BK, int N) {

    __shared__ float zrow[DDIM];
    __shared__ int   idxs[32];
    __shared__ float dots[32];

    const int row = blockIdx.x;
    const int t = threadIdx.x, w = t >> 6, lane = t & 63;

    {   float2 v = *(const float2*)(z + (size_t)row * DDIM + t * 2);
        zrow[t * 2] = v.x; zrow[t * 2 + 1] = v.y; }

    if (w == 0) {
        int k[12];
        const int* cp = cand + (size_t)row * (NS * 2 * 4) + lane * 12;
        #pragma unroll
        for (int q = 0; q < 12; ++q) k[q] = cp[q];
        for (int r = 0; r < 32; ++r) {
            int lk = k[0], lq = 0;
            #pragma unroll
            for (int q = 1; q < 12; ++q) if (k[q] > lk) { lk = k[q]; lq = q; }
            int wk = lk, wl = lane, wq = lq;
            #pragma unroll
            for (int off = 32; off > 0; off >>= 1) {
                int ok = __shfl_xor(wk, off, 64);
                int ol = __shfl_xor(wl, off, 64);
                int oq = __shfl_xor(wq, off, 64);
                if (ok > wk || (ok == wk && ol < wl)) { wk = ok; wl = ol; wq = oq; }
            }
            if (lane == wl) {
                #pragma unroll
                for (int q = 0; q < 12; ++q) if (q == wq) k[q] = (int)0x80000000;
            }
            if (lane == 0) {
                int j = wl * 12 + wq;         // position -> (split, h, slot)
                int split = j >> 3;
                int c = wk & 127, it = (wk >> 7) & 15;
                int gi = (it * NS + split) * 128 + c;
                idxs[r] = gi < N ? gi : 0;    // statistically impossible, fault-guard only
            }
        }
    }
    __syncthreads();

    // exact fp32 raw dot for the 32 survivors: wave w handles w*8..w*8+7
    #pragma unroll
    for (int jj = 0; jj < 8; ++jj) {
        const int ci = idxs[w * 8 + jj];
        const float* br = bank + (size_t)ci * DDIM + lane * 8;
        float4 x0 = *(const float4*)br;
        float4 x1 = *(const float4*)(br + 4);
        const float* zz = zrow + lane * 8;
        float4 z0 = *(const float4*)zz;
        float4 z1 = *(const float4*)(zz + 4);
        float s = x0.x*z0.x + x0.y*z0.y + x0.z*z0.z + x0.w*z0.w
                + x1.x*z1.x + x1.y*z1.y + x1.z*z1.z + x1.w*z1.w;
        #pragma unroll
        for (int off = 32; off > 0; off >>= 1) s += __shfl_xor(s, off, 64);
        if (lane == 0) dots[w * 8 + jj] = s;
    }
    __syncthreads();

    if (w == 0) {
        const float rzv = rz[row];
        float v; int ii;
        if (lane < 32) { ii = idxs[lane]; v = dots[lane] * rzv * rb[ii]; }
        else           { ii = IMAX;       v = NEG_INF; }
        for (int r = 0; r < 5; ++r) {
            float bv = v; int bi = ii;
            #pragma unroll
            for (int off = 32; off > 0; off >>= 1) {
                float ov = __shfl_xor(bv, off, 64);
                int   oi = __shfl_xor(bi, off, 64);
                if (ov > bv || (ov == bv && oi < bi)) { bv = ov; bi = oi; }
            }
            if (v == bv && ii == bi) { v = NEG_INF; ii = IMAX; }
            if (lane == 0) {
                out[(size_t)row * 5 + r]          = (float)bi;
                out[BK + (size_t)row * 5 + r]     = bv;
                out[2 * BK + (size_t)row * 5 + r] = (float)labels[bi];
            }
        }
    }
}

extern "C" void kernel_launch(void* const* d_in, const int* in_sizes, int n_in,
                              void* d_out, int out_size, void* d_ws, size_t ws_size,
                              hipStream_t stream) {
    const float* z    = (const float*)d_in[0];
    const float* bank = (const float*)d_in[1];
    const int*   lab  = (const int*)d_in[2];
    const int B = in_sizes[0] / DDIM;     // 1024
    const int N = in_sizes[1] / DDIM;     // 100000
    const int BK = out_size / 3;          // 5120
    const int nChunks = (N + 127) >> 7;   // 782
    float* out = (float*)d_out;
    char* ws = (char*)d_ws;

    const size_t o_rz = 0;                                       // B floats (pad 4K)
    const size_t o_rb = 4096;                                    // nChunks*128 floats
    const size_t o_zh = o_rb + (size_t)nChunks * 128 * 4;        // z f16 tile (1 MB)
    const size_t o_bh = o_zh + (size_t)(B / 128) * 16 * 8192;    // bank f16 tile (102.5 MB)
    const size_t o_cv = o_bh + (size_t)nChunks * 16 * 8192;      // cand keys (3 MB)

    float* rz = (float*)(ws + o_rz);
    float* rb = (float*)(ws + o_rb);
    unsigned* zh = (unsigned*)(ws + o_zh);
    unsigned* bh = (unsigned*)(ws + o_bh);
    int* cand = (int*)(ws + o_cv);

    split_tile_k<<<nChunks, 256, 0, stream>>>(bank, bh, rb, N);
    split_tile_k<<<B / 128, 256, 0, stream>>>(z, zh, rz, B);
    gemm_screen_k<<<dim3(NS, B / 128), 256, 0, stream>>>(zh, bh, rb, cand, N, nChunks);
    merge_rescore_k<<<B, 256, 0, stream>>>(cand, z, bank, rz, rb, lab, out, BK, N);
}